// Round 4
// baseline (21434.798 us; speedup 1.0000x reference)
//
#include <hip/hip_runtime.h>

typedef __bf16 bf16_t;
typedef __attribute__((ext_vector_type(8))) __bf16 bf16x8;
typedef __attribute__((ext_vector_type(4))) float f32x4;

__device__ __forceinline__ float gelu_exact(float x) {
    return 0.5f * x * (1.0f + erff(x * 0.70710678118654752f));
}

// ---------- attention GEMMs: round-3 pure-VALU tiled GEMM (validated-structure) ----------
// C[m][n] = sum_k A[m][k] * B[n][k], bf16 storage, fp32 compute.
// EPI: 0 = plain bf16 out; 1 = +bias, bf16 out
template<int EPI>
__global__ __launch_bounds__(256)
void vgemm(const bf16_t* __restrict__ A, int lda, long aBatch,
           const bf16_t* __restrict__ B, int ldb, long bBatch,
           bf16_t* __restrict__ C, int ldc, long cBatch,
           const float* __restrict__ bias, int K)
{
    __shared__ float As[32][72];
    __shared__ float Bs[32][72];
    const int t = threadIdx.x;
    const int tr = t >> 4, tc = t & 15;
    const int n0 = blockIdx.x * 64;
    const int m0 = blockIdx.y * 64;
    const int h  = blockIdx.z;
    A += (long)h * aBatch;
    B += (long)h * bBatch;
    C += (long)h * cBatch;

    float acc[4][4] = {};
    for (int k0 = 0; k0 < K; k0 += 32) {
        {
            int r = t >> 2, c = (t & 3) * 8;
            bf16x8 av = *(const bf16x8*)(A + (long)(m0 + r) * lda + (k0 + c));
            bf16x8 bv = *(const bf16x8*)(B + (long)(n0 + r) * ldb + (k0 + c));
            #pragma unroll
            for (int j = 0; j < 8; j++) {
                As[c + j][r] = (float)av[j];
                Bs[c + j][r] = (float)bv[j];
            }
        }
        __syncthreads();
        #pragma unroll 8
        for (int kk = 0; kk < 32; kk++) {
            float a[4], b[4];
            *(f32x4*)a = *(const f32x4*)&As[kk][tr * 4];
            *(f32x4*)b = *(const f32x4*)&Bs[kk][tc * 4];
            #pragma unroll
            for (int i = 0; i < 4; i++)
                #pragma unroll
                for (int j = 0; j < 4; j++)
                    acc[i][j] += a[i] * b[j];
        }
        __syncthreads();
    }
    #pragma unroll
    for (int i = 0; i < 4; i++) {
        int row = m0 + tr * 4 + i;
        #pragma unroll
        for (int j = 0; j < 4; j++) {
            int col = n0 + tc * 4 + j;
            float v = acc[i][j];
            if constexpr (EPI == 1) v += bias[col];
            C[(long)row * ldc + col] = (bf16_t)v;
        }
    }
}

// Vt[h][e][m] = V[h][m][e],  V[h][m][e] = Y[m*27648 + 18432 + h*1536 + e]
__global__ __launch_bounds__(256)
void transpose_v(const bf16_t* __restrict__ Y, bf16_t* __restrict__ Vt)
{
    __shared__ bf16_t tile[64][65];
    int h  = blockIdx.z;
    int e0 = blockIdx.x * 64;
    int m0 = blockIdx.y * 64;
    int tx = threadIdx.x & 63, ty = threadIdx.x >> 6;
    #pragma unroll
    for (int i = 0; i < 64; i += 4)
        tile[ty + i][tx] = Y[(long)(m0 + ty + i) * 27648 + 18432 + h * 1536 + (e0 + tx)];
    __syncthreads();
    #pragma unroll
    for (int i = 0; i < 64; i += 4)
        Vt[((long)h * 1536 + e0 + ty + i) * 2304 + (m0 + tx)] = tile[tx][ty + i];
}

// ---------- DUMB diagnostic kernels: no shuffles, no bf16 weights, 1 thread/output ----------

// LayerNorm, one block (256 thr) per row of 192. LDS tree reduction. fp32 in -> bf16 out.
__global__ __launch_bounds__(256)
void ln_dumb(const float* __restrict__ x, const float* __restrict__ g,
             const float* __restrict__ b, bf16_t* __restrict__ o)
{
    __shared__ float red[256];
    long row = blockIdx.x;
    int t = threadIdx.x;
    float v = (t < 192) ? x[row * 192 + t] : 0.f;
    red[t] = v;
    __syncthreads();
    for (int s = 128; s > 0; s >>= 1) { if (t < s) red[t] += red[t + s]; __syncthreads(); }
    float mean = red[0] * (1.f / 192.f);
    __syncthreads();
    float d = (t < 192) ? (v - mean) : 0.f;
    red[t] = d * d;
    __syncthreads();
    for (int s = 128; s > 0; s >>= 1) { if (t < s) red[t] += red[t + s]; __syncthreads(); }
    float rs = rsqrtf(red[0] * (1.f / 192.f) + 1e-5f);
    if (t < 192) o[row * 192 + t] = (bf16_t)(d * rs * g[t] + b[t]);
}

// softmax over 2304 bf16 logits (scale folded), in place. LDS tree, no shuffles.
__global__ __launch_bounds__(256)
void softmax_dumb(bf16_t* __restrict__ S)
{
    const float SC = 0.17677669529663687f;  // 32^-0.5
    __shared__ float red[256];
    long base = (long)blockIdx.x * 2304;
    int t = threadIdx.x;
    float v[9];
    float mx = -1e30f;
    #pragma unroll
    for (int i = 0; i < 9; ++i) {
        v[i] = (float)S[base + t + i * 256] * SC;
        mx = fmaxf(mx, v[i]);
    }
    red[t] = mx;
    __syncthreads();
    for (int s = 128; s > 0; s >>= 1) { if (t < s) red[t] = fmaxf(red[t], red[t + s]); __syncthreads(); }
    mx = red[0];
    __syncthreads();
    float sum = 0.f;
    #pragma unroll
    for (int i = 0; i < 9; ++i) { v[i] = __expf(v[i] - mx); sum += v[i]; }
    red[t] = sum;
    __syncthreads();
    for (int s = 128; s > 0; s >>= 1) { if (t < s) red[t] += red[t + s]; __syncthreads(); }
    float inv = 1.f / red[0];
    #pragma unroll
    for (int i = 0; i < 9; ++i) S[base + t + i * 256] = (bf16_t)(v[i] * inv);
}

// x1[m][c] = x[m][c] + sum_k O[m][k]*Wp[c][k] + pb[c].  1 block/row, 192 thr. fp32 weights.
__global__ __launch_bounds__(192)
void proj_dumb(const bf16_t* __restrict__ O, const float* __restrict__ Wp,
               const float* __restrict__ pb, const float* __restrict__ x,
               float* __restrict__ out)
{
    long m = blockIdx.x;
    int c = threadIdx.x;
    const bf16_t* orow = O + m * 192;
    const float* wrow = Wp + (long)c * 192;
    float s = 0.f;
    for (int k = 0; k < 192; ++k) s += (float)orow[k] * wrow[k];
    out[m * 192 + c] = x[m * 192 + c] + s + pb[c];
}

// hid[m][j] = gelu(sum_c A[m][c]*W1[j][c] + b1[j]).  grid (110592, 3), 256 thr. fp32 weights.
__global__ __launch_bounds__(256)
void fc1_dumb(const bf16_t* __restrict__ A, const float* __restrict__ W1,
              const float* __restrict__ b1, bf16_t* __restrict__ out)
{
    long m = blockIdx.x;
    int j = blockIdx.y * 256 + threadIdx.x;
    const bf16_t* ar = A + m * 192;
    const float* wrow = W1 + (long)j * 192;
    float s = 0.f;
    for (int c = 0; c < 192; ++c) s += (float)ar[c] * wrow[c];
    out[m * 768 + j] = (bf16_t)gelu_exact(s + b1[j]);
}

// out[m][c] += sum_j hid[m][j]*W2[c][j] + b2[c].  1 block/row, 192 thr. fp32 weights.
__global__ __launch_bounds__(192)
void fc2_dumb(const bf16_t* __restrict__ hid, const float* __restrict__ W2,
              const float* __restrict__ b2, float* __restrict__ out)
{
    long m = blockIdx.x;
    int c = threadIdx.x;
    const bf16_t* hr = hid + m * 768;
    const float* wrow = W2 + (long)c * 768;
    float s = 0.f;
    for (int j = 0; j < 768; ++j) s += (float)hr[j] * wrow[j];
    long idx = m * 192 + c;
    out[idx] = out[idx] + s + b2[c];
}

__global__ __launch_bounds__(256)
void cast_wq(const float* __restrict__ w, int n, bf16_t* __restrict__ o)
{
    int i = blockIdx.x * 256 + threadIdx.x;
    if (i < n) o[i] = (bf16_t)w[i];
}

extern "C" void kernel_launch(void* const* d_in, const int* in_sizes, int n_in,
                              void* d_out, int out_size, void* d_ws, size_t ws_size,
                              hipStream_t stream)
{
    (void)in_sizes; (void)n_in; (void)out_size; (void)ws_size;
    const float* x      = (const float*)d_in[0];
    const float* n1g    = (const float*)d_in[1];
    const float* n1b    = (const float*)d_in[2];
    const float* qkv_w  = (const float*)d_in[3];
    const float* qkv_b  = (const float*)d_in[4];
    const float* proj_w = (const float*)d_in[5];
    const float* proj_b = (const float*)d_in[6];
    const float* n2g    = (const float*)d_in[7];
    const float* n2b    = (const float*)d_in[8];
    const float* fc1_w  = (const float*)d_in[9];
    const float* fc1_b  = (const float*)d_in[10];
    const float* fc2_w  = (const float*)d_in[11];
    const float* fc2_b  = (const float*)d_in[12];
    float* out = (float*)d_out;

    char* ws = (char*)d_ws;
    size_t off = 0;
    auto alloc = [&](size_t nbytes) -> void* {
        off = (off + 255) & ~(size_t)255;
        void* p = ws + off;
        off += nbytes;
        return p;
    };

    bf16_t* Wq   = (bf16_t*)alloc((size_t)576 * 192 * 2);
    bf16_t* Hbuf = (bf16_t*)alloc((size_t)110592 * 192 * 2);   // ln1 out -> O -> ln2 out
    bf16_t* Qkv  = (bf16_t*)alloc((size_t)110592 * 768 * 2);   // qkv(576)+Vt tail -> fc1(768)
    bf16_t* Vt   = Qkv + (size_t)110592 * 576;
    bf16_t* Sbuf = (bf16_t*)d_out;                              // 63.7 MB <= 85 MB, dead until proj

    cast_wq<<<432, 256, 0, stream>>>(qkv_w, 576 * 192, Wq);
    // LN1: x -> Hbuf (bf16)
    ln_dumb<<<110592, 256, 0, stream>>>(x, n1g, n1b, Hbuf);
    // QKV: (110592x192)@(576x192)^T + b -> Qkv
    vgemm<1><<<dim3(9, 1728, 1), 256, 0, stream>>>(
        Hbuf, 192, 0, Wq, 192, 0, Qkv, 576, 0, qkv_b, 192);
    // Vt[h][e][m] = V[h][m][e]
    transpose_v<<<dim3(24, 36, 6), 256, 0, stream>>>(Qkv, Vt);
    // S = Q @ K^T per head (z=6): 2304x2304, K=1536
    vgemm<0><<<dim3(36, 36, 6), 256, 0, stream>>>(
        Qkv, 27648, 1536, Qkv + 9216, 27648, 1536,
        Sbuf, 2304, (long)2304 * 2304, nullptr, 1536);
    // softmax rows (scale inside), in place
    softmax_dumb<<<13824, 256, 0, stream>>>(Sbuf);
    // O = P @ Vt^T per head: 2304x1536, K=2304
    vgemm<0><<<dim3(24, 36, 6), 256, 0, stream>>>(
        Sbuf, 2304, (long)2304 * 2304, Vt, 2304, (long)1536 * 2304,
        Hbuf, 9216, 1536, nullptr, 2304);
    // x1 = x + O @ Wp^T + pb  -> out (fp32), dumb
    proj_dumb<<<110592, 192, 0, stream>>>(Hbuf, proj_w, proj_b, x, out);
    // LN2: x1 -> Hbuf (bf16), dumb
    ln_dumb<<<110592, 256, 0, stream>>>(out, n2g, n2b, Hbuf);
    // fc1 + gelu -> Qkv (768 cols), dumb
    fc1_dumb<<<dim3(110592, 3, 1), 256, 0, stream>>>(Hbuf, fc1_w, fc1_b, Qkv);
    // fc2 + resid -> out, dumb
    fc2_dumb<<<110592, 192, 0, stream>>>(Qkv, fc2_w, fc2_b, out);
}